// Round 2
// baseline (1667.929 us; speedup 1.0000x reference)
//
#include <hip/hip_runtime.h>
#include <hip/hip_bf16.h>

#define Bb 8
#define Nn 1024
#define DIN 512
#define Cc 256
#define Tt 8192
#define Kk 31
#define Ll 3
#define PCONV (Kk*Cc)   // 7936

typedef __attribute__((ext_vector_type(8))) short short8;
typedef __attribute__((ext_vector_type(4))) float f32x4;

__device__ __forceinline__ ushort f2bf(float f) {
  union { __hip_bfloat16 h; unsigned short u; } cv;
  cv.h = __float2bfloat16(f);
  return cv.u;
}

// ---------------- idx: per-batch cumsum of durations + scatter fill ----------
__global__ void k_idx(const int* __restrict__ dur, int* __restrict__ idx) {
  int b = blockIdx.x, tid = threadIdx.x;
  __shared__ int cum[Nn];
  int d = dur[b * Nn + tid];
  cum[tid] = d;
  __syncthreads();
  for (int off = 1; off < Nn; off <<= 1) {
    int o = (tid >= off) ? cum[tid - off] : 0;
    __syncthreads();
    cum[tid] += o;
    __syncthreads();
  }
  int end = cum[tid], start = end - d;
  if (start < 0) start = 0;
  if (end > Tt) end = Tt;
  for (int t = start; t < end; ++t) idx[b * Tt + t] = tid;
}

// ---------------- f32 -> bf16 cast (pooled) ----------------------------------
__global__ void k_cast(const float* __restrict__ in, ushort* __restrict__ out, int n4) {
  int i = blockIdx.x * 256 + threadIdx.x;
  if (i >= n4) return;
  float4 v = reinterpret_cast<const float4*>(in)[i];
  ushort4 o;
  o.x = f2bf(v.x); o.y = f2bf(v.y); o.z = f2bf(v.z); o.w = f2bf(v.w);
  reinterpret_cast<ushort4*>(out)[i] = o;
}

// ---------------- W_in^T -> bf16 [co][din] -----------------------------------
__global__ void k_winT(const float* __restrict__ Win, ushort* __restrict__ out) {
  int co = blockIdx.x;
  for (int d = threadIdx.x; d < DIN; d += 256)
    out[(size_t)co * DIN + d] = f2bf(Win[(size_t)d * Cc + co]);
}

// ---------------- W_pos^T -> bf16 [co][ci] -----------------------------------
__global__ void k_wpos(const float* __restrict__ Wpos, ushort* __restrict__ out) {
  int co = blockIdx.x, ci = threadIdx.x;
  out[(size_t)co * Cc + ci] = f2bf(Wpos[(size_t)ci * Cc + co]);
}

// ------------- conv_w [l][co][ci][k] -> bf16 [l][co][k*256+ci] ---------------
__global__ void k_wconv(const float* __restrict__ w, ushort* __restrict__ wT) {
  int blk = blockIdx.x;            // l*256 + co
  int tid = threadIdx.x;
  __shared__ ushort t_[Kk][Cc];
  const float* src = w + (size_t)blk * (Cc * Kk);
  for (int i = tid; i < Cc * Kk; i += 256) {
    int ci = i / Kk, k = i - ci * Kk;     // src flat = ci*31 + k
    t_[k][ci] = f2bf(src[i]);
  }
  __syncthreads();
  ushort* dst = wT + (size_t)blk * PCONV;
  const ushort* tf = &t_[0][0];
  for (int i = tid; i < PCONV; i += 256) dst[i] = tf[i];
}

// ---------------- sinusoidal positional embedding -> bf16 --------------------
__global__ void k_pos(const float* __restrict__ rel, ushort* __restrict__ pos) {
  int tid = threadIdx.x;
  int row = blockIdx.x * 4 + (tid >> 6);     // 0..65535 (b*T + t)
  int c0 = (tid & 63) * 4;
  float x = rel[row];
  ushort4 o;
  ushort tmp[4];
#pragma unroll
  for (int j = 0; j < 4; ++j) {
    int c = c0 + j;
    int half = c >> 7;
    int fidx = c & 127;
    float freq = __expf(-9.210340371976184f * (float)fidx * (1.0f / 127.0f));
    float a = x * freq;
    tmp[j] = f2bf(half ? __cosf(a) : __sinf(a));
  }
  o.x = tmp[0]; o.y = tmp[1]; o.z = tmp[2]; o.w = tmp[3];
  *reinterpret_cast<ushort4*>(pos + ((size_t)row << 8) + c0) = o;
}

// ---------------- LayerNorm (+optional exact GELU -> bf16) -------------------
// GELU=1: write bf16 h; GELU=0: write f32 (final LN, in-place ok)
template <int GELU>
__global__ void k_ln(const float* __restrict__ X, const float* __restrict__ g,
                     const float* __restrict__ bta, ushort* __restrict__ H,
                     float* __restrict__ Xout) {
  int tid = threadIdx.x;
  int lane = tid & 63;
  int row = blockIdx.x * 4 + (tid >> 6);
  f32x4 v = reinterpret_cast<const f32x4*>(X + ((size_t)row << 8))[lane];
  float s = v[0] + v[1] + v[2] + v[3];
  float s2 = v[0]*v[0] + v[1]*v[1] + v[2]*v[2] + v[3]*v[3];
#pragma unroll
  for (int off = 32; off; off >>= 1) {
    s += __shfl_xor(s, off);
    s2 += __shfl_xor(s2, off);
  }
  float mu = s * (1.0f / 256.0f);
  float var = s2 * (1.0f / 256.0f) - mu * mu;
  float rs = rsqrtf(var + 1e-5f);
  f32x4 gv = reinterpret_cast<const f32x4*>(g)[lane];
  f32x4 bv = reinterpret_cast<const f32x4*>(bta)[lane];
  f32x4 n;
#pragma unroll
  for (int j = 0; j < 4; ++j) n[j] = (v[j] - mu) * rs * gv[j] + bv[j];
  if (GELU) {
    ushort4 o;
    ushort tmp[4];
#pragma unroll
    for (int j = 0; j < 4; ++j) {
      float x = n[j];
      tmp[j] = f2bf(0.5f * x * (1.0f + erff(x * 0.70710678118654752f)));
    }
    o.x = tmp[0]; o.y = tmp[1]; o.z = tmp[2]; o.w = tmp[3];
    reinterpret_cast<ushort4*>(H + ((size_t)row << 8))[lane] = o;
  } else {
    reinterpret_cast<f32x4*>(Xout + ((size_t)row << 8))[lane] = n;
  }
}

// ---------------- bf16 MFMA GEMM, 128x128 tile, BK=64 ------------------------
// MODE 0: proj-out   : out = acc + bias1[col]                    (A=pooled bf16, lda=512)
// MODE 1: pos        : out = acc + proj[gather] + bias1[col]     (A=pos bf16)
// MODE 2: conv+resid : out += acc + bias1[col]  (A=h bf16, im2col over k)
#define BM 128
#define BN 128
#define BK 64

template <int MODE>
__global__ __launch_bounds__(256) void k_gemm(
    const ushort* __restrict__ A, const ushort* __restrict__ Bw,
    float* __restrict__ XO, const float* __restrict__ proj,
    const int* __restrict__ idx, const float* __restrict__ bias1,
    int P, int lda) {
  __shared__ __align__(16) char lsA[BM * BK * 2];
  __shared__ __align__(16) char lsB[BN * BK * 2];
  int tid = threadIdx.x;
  int tm = blockIdx.x, cn = blockIdx.y, b = blockIdx.z;
  int t0 = tm * BM, co0 = cn * BN;
  int rowbase = b * Tt;     // MODE 0 has gridDim.z==1 -> 0
  int lane = tid & 63, wid = tid >> 6;
  int wm = wid >> 1, wn = wid & 1;

  f32x4 acc[4][4];
#pragma unroll
  for (int i = 0; i < 4; ++i)
#pragma unroll
    for (int j = 0; j < 4; ++j) acc[i][j] = (f32x4){0.f, 0.f, 0.f, 0.f};

  int steps = P >> 6;
  for (int s = 0; s < steps; ++s) {
    int p0 = s << 6;
    int k, ci0;
    if (MODE == 2) { k = s >> 2; ci0 = (s & 3) << 6; }
    else           { k = 0;      ci0 = p0; }
    __syncthreads();
    // stage A and B tiles: 128 rows x 128 bytes each, 16B per thread-chunk
#pragma unroll
    for (int it = 0; it < 4; ++it) {
      int ch = tid + (it << 8);
      int r = ch >> 3, cb = (ch & 7) << 4;
      int off = (r * 128 + cb) ^ ((r & 7) << 4);
      // A
      uint4 va = make_uint4(0u, 0u, 0u, 0u);
      int st = t0 + r + k - (Kk - 1) * (MODE == 2 ? 1 : 0);
      bool valid = (MODE == 2) ? (st >= 0) : true;
      if (valid)
        va = *(reinterpret_cast<const uint4*>(A + (size_t)(rowbase + st) * lda + ci0) + (cb >> 4));
      *reinterpret_cast<uint4*>(lsA + off) = va;
      // B
      uint4 vb = *(reinterpret_cast<const uint4*>(Bw + (size_t)(co0 + r) * P + p0) + (cb >> 4));
      *reinterpret_cast<uint4*>(lsB + off) = vb;
    }
    __syncthreads();
#pragma unroll
    for (int h2 = 0; h2 < 2; ++h2) {
      int kb = h2 * 64 + ((lane >> 4) << 4);
      short8 af[4], bf[4];
#pragma unroll
      for (int fi = 0; fi < 4; ++fi) {
        int ra = wm * 64 + fi * 16 + (lane & 15);
        af[fi] = *reinterpret_cast<const short8*>(lsA + ((ra * 128 + kb) ^ ((ra & 7) << 4)));
        int rb = wn * 64 + fi * 16 + (lane & 15);
        bf[fi] = *reinterpret_cast<const short8*>(lsB + ((rb * 128 + kb) ^ ((rb & 7) << 4)));
      }
#pragma unroll
      for (int fi = 0; fi < 4; ++fi)
#pragma unroll
        for (int fj = 0; fj < 4; ++fj)
          acc[fi][fj] = __builtin_amdgcn_mfma_f32_16x16x32_bf16(af[fi], bf[fj], acc[fi][fj], 0, 0, 0);
    }
  }
  // epilogue: C/D layout col=lane&15, row=(lane>>4)*4+r  [guide §3, m89]
#pragma unroll
  for (int fi = 0; fi < 4; ++fi) {
#pragma unroll
    for (int fj = 0; fj < 4; ++fj) {
#pragma unroll
      for (int r = 0; r < 4; ++r) {
        int row = t0 + wm * 64 + fi * 16 + ((lane >> 4) << 2) + r;
        int col = co0 + wn * 64 + fj * 16 + (lane & 15);
        size_t go = ((size_t)(rowbase + row) << 8) + col;
        float v = acc[fi][fj][r];
        if (MODE == 0) {
          XO[go] = v + bias1[col];
        } else if (MODE == 1) {
          int ix = idx[b * Tt + row];
          ix = min(max(ix, 0), Nn - 1);
          XO[go] = v + proj[((size_t)(b * Nn + ix) << 8) + col] + bias1[col];
        } else {
          XO[go] += v + bias1[col];
        }
      }
    }
  }
}

extern "C" void kernel_launch(void* const* d_in, const int* in_sizes, int n_in,
                              void* d_out, int out_size, void* d_ws, size_t ws_size,
                              hipStream_t stream) {
  const float* pooled = (const float*)d_in[0];
  const int*   durations = (const int*)d_in[1];
  const float* rel  = (const float*)d_in[2];
  const float* Win  = (const float*)d_in[3];
  const float* bin  = (const float*)d_in[4];
  const float* Wpos = (const float*)d_in[5];
  const float* bpos = (const float*)d_in[6];
  const float* lng  = (const float*)d_in[7];
  const float* lnb  = (const float*)d_in[8];
  const float* convw = (const float*)d_in[9];
  const float* convb = (const float*)d_in[10];
  const float* outg = (const float*)d_in[11];
  const float* outb = (const float*)d_in[12];
  float* X = (float*)d_out;

  char* ws = (char*)d_ws;
  int*    idx      = (int*)ws;                          // 256 KB
  float*  proj     = (float*)(ws + 262144);             // 8 MB
  ushort* hbuf     = (ushort*)(ws + 8650752);           // 32 MB (pos emb, then h)
  ushort* wposT    = (ushort*)(ws + 42205184);          // 128 KB
  ushort* wT3      = (ushort*)(ws + 42336256);          // 12.19 MB
  ushort* pooledbf = (ushort*)(ws + 54525952);          // 8 MB
  ushort* winT     = (ushort*)(ws + 62914560);          // 256 KB  (end ~60.2 MB)

  k_idx<<<Bb, Nn, 0, stream>>>(durations, idx);
  k_cast<<<4096, 256, 0, stream>>>(pooled, pooledbf, (Bb * Nn * DIN) / 4);
  k_winT<<<Cc, 256, 0, stream>>>(Win, winT);
  k_wconv<<<Ll * Cc, 256, 0, stream>>>(convw, wT3);
  k_wpos<<<Cc, Cc, 0, stream>>>(Wpos, wposT);
  k_pos<<<(Bb * Tt) / 4, 256, 0, stream>>>(rel, hbuf);

  // in_proj: proj[n, co] = pooled @ W_in + b_in    (8192 x 512 x 256)
  k_gemm<0><<<dim3(64, 2, 1), 256, 0, stream>>>(pooledbf, winT, proj, nullptr, nullptr, bin, DIN, DIN);
  // x = gather(proj, idx) + pos @ W_pos + b_pos    (65536 x 256 x 256)
  k_gemm<1><<<dim3(64, 2, Bb), 256, 0, stream>>>(hbuf, wposT, X, proj, idx, bpos, Cc, Cc);

  for (int l = 0; l < Ll; ++l) {
    k_ln<1><<<(Bb * Tt) / 4, 256, 0, stream>>>(X, lng + l * Cc, lnb + l * Cc, hbuf, nullptr);
    k_gemm<2><<<dim3(64, 2, Bb), 256, 0, stream>>>(hbuf, wT3 + (size_t)l * Cc * PCONV, X,
                                                   nullptr, nullptr, convb + l * Cc, PCONV, Cc);
  }
  k_ln<0><<<(Bb * Tt) / 4, 256, 0, stream>>>(X, outg, outb, nullptr, X);
}

// Round 3
// 1266.441 us; speedup vs baseline: 1.3170x; 1.3170x over previous
//
#include <hip/hip_runtime.h>
#include <hip/hip_bf16.h>

#define Bb 8
#define Nn 1024
#define DIN 512
#define Cc 256
#define Tt 8192
#define Kk 31
#define Ll 3
#define PCONV (Kk*Cc)   // 7936
#define TPAD (Tt+32)    // 32 zero rows in front of each batch of h

typedef __attribute__((ext_vector_type(8))) short short8;
typedef __attribute__((ext_vector_type(4))) float f32x4;

__device__ __forceinline__ ushort f2bf(float f) {
  union { __hip_bfloat16 h; unsigned short u; } cv;
  cv.h = __float2bfloat16(f);
  return cv.u;
}

// direct global->LDS DMA, 16B per lane; lptr must be wave-uniform (HW adds lane*16)
__device__ __forceinline__ void gload16(const void* g, void* l) {
  __builtin_amdgcn_global_load_lds((const __attribute__((address_space(1))) void*)g,
                                   (__attribute__((address_space(3))) void*)l, 16, 0, 0);
}

// ---------------- idx: per-batch cumsum of durations + scatter fill ----------
__global__ void k_idx(const int* __restrict__ dur, int* __restrict__ idx) {
  int b = blockIdx.x, tid = threadIdx.x;
  __shared__ int cum[Nn];
  int d = dur[b * Nn + tid];
  cum[tid] = d;
  __syncthreads();
  for (int off = 1; off < Nn; off <<= 1) {
    int o = (tid >= off) ? cum[tid - off] : 0;
    __syncthreads();
    cum[tid] += o;
    __syncthreads();
  }
  int end = cum[tid], start = end - d;
  if (start < 0) start = 0;
  if (end > Tt) end = Tt;
  for (int t = start; t < end; ++t) idx[b * Tt + t] = tid;
}

// ---------------- f32 -> bf16 cast (pooled) ----------------------------------
__global__ void k_cast(const float* __restrict__ in, ushort* __restrict__ out, int n4) {
  int i = blockIdx.x * 256 + threadIdx.x;
  if (i >= n4) return;
  float4 v = reinterpret_cast<const float4*>(in)[i];
  ushort4 o;
  o.x = f2bf(v.x); o.y = f2bf(v.y); o.z = f2bf(v.z); o.w = f2bf(v.w);
  reinterpret_cast<ushort4*>(out)[i] = o;
}

// ---------------- W_in^T -> bf16 [co][din] -----------------------------------
__global__ void k_winT(const float* __restrict__ Win, ushort* __restrict__ out) {
  int co = blockIdx.x;
  for (int d = threadIdx.x; d < DIN; d += 256)
    out[(size_t)co * DIN + d] = f2bf(Win[(size_t)d * Cc + co]);
}

// ---------------- W_pos^T -> bf16 [co][ci] -----------------------------------
__global__ void k_wpos(const float* __restrict__ Wpos, ushort* __restrict__ out) {
  int co = blockIdx.x, ci = threadIdx.x;
  out[(size_t)co * Cc + ci] = f2bf(Wpos[(size_t)ci * Cc + co]);
}

// ------------- conv_w [l][co][ci][k] -> bf16 [l][co][k*256+ci] ---------------
__global__ void k_wconv(const float* __restrict__ w, ushort* __restrict__ wT) {
  int blk = blockIdx.x;            // l*256 + co
  int tid = threadIdx.x;
  __shared__ ushort t_[Kk][Cc];
  const float* src = w + (size_t)blk * (Cc * Kk);
  for (int i = tid; i < Cc * Kk; i += 256) {
    int ci = i / Kk, k = i - ci * Kk;     // src flat = ci*31 + k
    t_[k][ci] = f2bf(src[i]);
  }
  __syncthreads();
  ushort* dst = wT + (size_t)blk * PCONV;
  const ushort* tf = &t_[0][0];
  for (int i = tid; i < PCONV; i += 256) dst[i] = tf[i];
}

// ---------------- zero the 32 pad rows of each batch in hpad -----------------
__global__ void k_zpad(ushort* __restrict__ hpad) {
  size_t base = (size_t)blockIdx.x * TPAD * Cc;  // pad rows are first 32 rows
  uint4 z = make_uint4(0u, 0u, 0u, 0u);
  for (int i = threadIdx.x; i < (32 * Cc) / 8; i += 256)
    reinterpret_cast<uint4*>(hpad + base)[i] = z;
}

// ---------------- sinusoidal positional embedding -> bf16 --------------------
__global__ void k_pos(const float* __restrict__ rel, ushort* __restrict__ pos) {
  int tid = threadIdx.x;
  int row = blockIdx.x * 4 + (tid >> 6);     // 0..65535 (b*T + t)
  int c0 = (tid & 63) * 4;
  float x = rel[row];
  ushort4 o;
  ushort tmp[4];
#pragma unroll
  for (int j = 0; j < 4; ++j) {
    int c = c0 + j;
    int half = c >> 7;
    int fidx = c & 127;
    float freq = __expf(-9.210340371976184f * (float)fidx * (1.0f / 127.0f));
    float a = x * freq;
    tmp[j] = f2bf(half ? __cosf(a) : __sinf(a));
  }
  o.x = tmp[0]; o.y = tmp[1]; o.z = tmp[2]; o.w = tmp[3];
  *reinterpret_cast<ushort4*>(pos + ((size_t)row << 8) + c0) = o;
}

// ---------------- LayerNorm (+optional exact GELU -> bf16) -------------------
// GELU=1: write bf16 h into PADDED hpad layout; GELU=0: write f32 (final LN)
template <int GELU>
__global__ void k_ln(const float* __restrict__ X, const float* __restrict__ g,
                     const float* __restrict__ bta, ushort* __restrict__ H,
                     float* __restrict__ Xout) {
  int tid = threadIdx.x;
  int lane = tid & 63;
  int row = blockIdx.x * 4 + (tid >> 6);
  f32x4 v = reinterpret_cast<const f32x4*>(X + ((size_t)row << 8))[lane];
  float s = v[0] + v[1] + v[2] + v[3];
  float s2 = v[0]*v[0] + v[1]*v[1] + v[2]*v[2] + v[3]*v[3];
#pragma unroll
  for (int off = 32; off; off >>= 1) {
    s += __shfl_xor(s, off);
    s2 += __shfl_xor(s2, off);
  }
  float mu = s * (1.0f / 256.0f);
  float var = s2 * (1.0f / 256.0f) - mu * mu;
  float rs = rsqrtf(var + 1e-5f);
  f32x4 gv = reinterpret_cast<const f32x4*>(g)[lane];
  f32x4 bv = reinterpret_cast<const f32x4*>(bta)[lane];
  f32x4 n;
#pragma unroll
  for (int j = 0; j < 4; ++j) n[j] = (v[j] - mu) * rs * gv[j] + bv[j];
  if (GELU) {
    ushort4 o;
    ushort tmp[4];
#pragma unroll
    for (int j = 0; j < 4; ++j) {
      float x = n[j];
      tmp[j] = f2bf(0.5f * x * (1.0f + erff(x * 0.70710678118654752f)));
    }
    o.x = tmp[0]; o.y = tmp[1]; o.z = tmp[2]; o.w = tmp[3];
    size_t hrow = (size_t)row + ((size_t)(row >> 13) << 5) + 32;  // padded layout
    reinterpret_cast<ushort4*>(H + (hrow << 8))[lane] = o;
  } else {
    reinterpret_cast<f32x4*>(Xout + ((size_t)row << 8))[lane] = n;
  }
}

// ---------------- bf16 MFMA GEMM, 128x128 tile, BK=64, global_load_lds -------
// MODE 0: proj-out   : out = acc + bias1[col]                    (A=pooled bf16, lda=512)
// MODE 1: pos        : out = acc + proj[gather] + bias1[col]     (A=pos bf16)
// MODE 2: conv+resid : out += acc + bias1[col]  (A=hpad bf16, im2col over k, pre-padded)
#define BM 128
#define BN 128
#define BK 64

template <int MODE>
__global__ __launch_bounds__(256) void k_gemm(
    const ushort* __restrict__ A, const ushort* __restrict__ Bw,
    float* __restrict__ XO, const float* __restrict__ proj,
    const int* __restrict__ idx, const float* __restrict__ bias1,
    int P, int lda) {
  __shared__ __align__(16) char lsA[BM * BK * 2];   // 16 KB, linear (pre-swizzled src)
  __shared__ __align__(16) char lsB[BN * BK * 2];   // 16 KB
  int tid = threadIdx.x;
  int tm = blockIdx.x, cn = blockIdx.y, b = blockIdx.z;
  int t0 = tm * BM, co0 = cn * BN;
  int lane = tid & 63, wid = tid >> 6;
  int wm = wid >> 1, wn = wid & 1;

  // per-lane pre-swizzled source column: lane l covers LDS bytes (chunk*1024 + l*16);
  // linear LDS row = chunk*8 + (l>>3); source col element = ((l&7) ^ (l>>3)) * 8
  int srow = lane >> 3;
  int scol = ((lane & 7) ^ srow) << 3;

  size_t rowoff;
  if (MODE == 0) rowoff = 0;
  else if (MODE == 1) rowoff = (size_t)b * Tt;
  else rowoff = (size_t)b * TPAD;

  f32x4 acc[4][4];
#pragma unroll
  for (int i = 0; i < 4; ++i)
#pragma unroll
    for (int j = 0; j < 4; ++j) acc[i][j] = (f32x4){0.f, 0.f, 0.f, 0.f};

  int steps = P >> 6;
  for (int s = 0; s < steps; ++s) {
    int p0 = s << 6;
    int k, ci0;
    if (MODE == 2) { k = (s >> 2) + 2; ci0 = (s & 3) << 6; }  // +2: pad offset (32-30)
    else           { k = 0;            ci0 = p0; }
    __syncthreads();
    // stage A and B tiles: 16 chunks of 1KB each, 4 per wave, DMA 16B/lane
#pragma unroll
    for (int i = 0; i < 4; ++i) {
      int j = (wid << 2) + i;           // chunk 0..15
      int r = (j << 3) + srow;          // tile row this lane sources
      const ushort* ga = A + (rowoff + (size_t)(t0 + r + k)) * lda + ci0 + scol;
      gload16(ga, lsA + (j << 10));
      const ushort* gb = Bw + (size_t)(co0 + r) * P + p0 + scol;
      gload16(gb, lsB + (j << 10));
    }
    __syncthreads();
#pragma unroll
    for (int h2 = 0; h2 < 2; ++h2) {
      int kb = h2 * 64 + ((lane >> 4) << 4);
      short8 af[4], bf[4];
#pragma unroll
      for (int fi = 0; fi < 4; ++fi) {
        int ra = wm * 64 + fi * 16 + (lane & 15);
        af[fi] = *reinterpret_cast<const short8*>(lsA + ((ra * 128 + kb) ^ ((ra & 7) << 4)));
        int rb = wn * 64 + fi * 16 + (lane & 15);
        bf[fi] = *reinterpret_cast<const short8*>(lsB + ((rb * 128 + kb) ^ ((rb & 7) << 4)));
      }
#pragma unroll
      for (int fi = 0; fi < 4; ++fi)
#pragma unroll
        for (int fj = 0; fj < 4; ++fj)
          acc[fi][fj] = __builtin_amdgcn_mfma_f32_16x16x32_bf16(af[fi], bf[fj], acc[fi][fj], 0, 0, 0);
    }
  }
  // epilogue: C/D layout col=lane&15, row=(lane>>4)*4+r  [guide §3, m89]
  size_t rowbase = (size_t)b * Tt;
#pragma unroll
  for (int fi = 0; fi < 4; ++fi) {
#pragma unroll
    for (int fj = 0; fj < 4; ++fj) {
#pragma unroll
      for (int r = 0; r < 4; ++r) {
        int row = t0 + wm * 64 + fi * 16 + ((lane >> 4) << 2) + r;
        int col = co0 + wn * 64 + fj * 16 + (lane & 15);
        size_t go = ((rowbase + row) << 8) + col;
        float v = acc[fi][fj][r];
        if (MODE == 0) {
          XO[go] = v + bias1[col];
        } else if (MODE == 1) {
          int ix = idx[b * Tt + row];
          ix = min(max(ix, 0), Nn - 1);
          XO[go] = v + proj[((size_t)(b * Nn + ix) << 8) + col] + bias1[col];
        } else {
          XO[go] += v + bias1[col];
        }
      }
    }
  }
}

extern "C" void kernel_launch(void* const* d_in, const int* in_sizes, int n_in,
                              void* d_out, int out_size, void* d_ws, size_t ws_size,
                              hipStream_t stream) {
  const float* pooled = (const float*)d_in[0];
  const int*   durations = (const int*)d_in[1];
  const float* rel  = (const float*)d_in[2];
  const float* Win  = (const float*)d_in[3];
  const float* bin  = (const float*)d_in[4];
  const float* Wpos = (const float*)d_in[5];
  const float* bpos = (const float*)d_in[6];
  const float* lng  = (const float*)d_in[7];
  const float* lnb  = (const float*)d_in[8];
  const float* convw = (const float*)d_in[9];
  const float* convb = (const float*)d_in[10];
  const float* outg = (const float*)d_in[11];
  const float* outb = (const float*)d_in[12];
  float* X = (float*)d_out;

  char* ws = (char*)d_ws;
  int*    idx      = (int*)ws;                          // 256 KB
  float*  proj     = (float*)(ws + 262144);             // 8 MB      -> end  8650752
  ushort* pos      = (ushort*)(ws + 8650752);           // 32 MB (pos emb; later hpad)
  ushort* hpad     = (ushort*)(ws + 8650752);           // 33.7 MB   -> end 42336256
  ushort* wposT    = (ushort*)(ws + 42336256);          // 128 KB    -> end 42467328
  ushort* wT3      = (ushort*)(ws + 42467328);          // 11.6 MB   -> end 54657024
  ushort* pooledbf = (ushort*)(ws + 54657024);          // 8 MB      -> end 63045632
  ushort* winT     = (ushort*)(ws + 63045632);          // 256 KB    -> end 63307776

  k_idx<<<Bb, Nn, 0, stream>>>(durations, idx);
  k_cast<<<4096, 256, 0, stream>>>(pooled, pooledbf, (Bb * Nn * DIN) / 4);
  k_winT<<<Cc, 256, 0, stream>>>(Win, winT);
  k_wconv<<<Ll * Cc, 256, 0, stream>>>(convw, wT3);
  k_wpos<<<Cc, Cc, 0, stream>>>(Wpos, wposT);
  k_pos<<<(Bb * Tt) / 4, 256, 0, stream>>>(rel, pos);

  // in_proj: proj[n, co] = pooled @ W_in + b_in    (8192 x 512 x 256)
  k_gemm<0><<<dim3(64, 2, 1), 256, 0, stream>>>(pooledbf, winT, proj, nullptr, nullptr, bin, DIN, DIN);
  // x = gather(proj, idx) + pos @ W_pos + b_pos    (65536 x 256 x 256)
  k_gemm<1><<<dim3(64, 2, Bb), 256, 0, stream>>>(pos, wposT, X, proj, idx, bpos, Cc, Cc);
  // pos consumed -> region becomes hpad; zero the pad rows once
  k_zpad<<<Bb, 256, 0, stream>>>(hpad);

  for (int l = 0; l < Ll; ++l) {
    k_ln<1><<<(Bb * Tt) / 4, 256, 0, stream>>>(X, lng + l * Cc, lnb + l * Cc, hpad, nullptr);
    k_gemm<2><<<dim3(64, 2, Bb), 256, 0, stream>>>(hpad, wT3 + (size_t)l * Cc * PCONV, X,
                                                   nullptr, nullptr, convb + l * Cc, PCONV, Cc);
  }
  k_ln<0><<<(Bb * Tt) / 4, 256, 0, stream>>>(X, outg, outb, nullptr, X);
}

// Round 9
// 983.407 us; speedup vs baseline: 1.6961x; 1.2878x over previous
//
#include <hip/hip_runtime.h>
#include <hip/hip_bf16.h>

#define Bb 8
#define Nn 1024
#define DIN 512
#define Cc 256
#define Tt 8192
#define Kk 31
#define Ll 3
#define PCONV (Kk*Cc)   // 7936
#define TPAD (Tt+32)    // 32 zero rows in front of each batch of h
#define NT 124          // PCONV/64 K-steps

typedef __attribute__((ext_vector_type(8))) short short8;
typedef __attribute__((ext_vector_type(4))) float f32x4;

__device__ __forceinline__ ushort f2bf(float f) {
  union { __hip_bfloat16 h; unsigned short u; } cv;
  cv.h = __float2bfloat16(f);
  return cv.u;
}

// direct global->LDS DMA, 16B per lane; LDS ptr wave-uniform (HW adds lane*16)
__device__ __forceinline__ void gload16(const void* g, void* l) {
  __builtin_amdgcn_global_load_lds((const __attribute__((address_space(1))) void*)g,
                                   (__attribute__((address_space(3))) void*)l, 16, 0, 0);
}

// ---------------- idx: per-batch cumsum of durations + scatter fill ----------
__global__ void k_idx(const int* __restrict__ dur, int* __restrict__ idx) {
  int b = blockIdx.x, tid = threadIdx.x;
  __shared__ int cum[Nn];
  int d = dur[b * Nn + tid];
  cum[tid] = d;
  __syncthreads();
  for (int off = 1; off < Nn; off <<= 1) {
    int o = (tid >= off) ? cum[tid - off] : 0;
    __syncthreads();
    cum[tid] += o;
    __syncthreads();
  }
  int end = cum[tid], start = end - d;
  if (start < 0) start = 0;
  if (end > Tt) end = Tt;
  for (int t = start; t < end; ++t) idx[b * Tt + t] = tid;
}

// ---------------- f32 -> bf16 cast (pooled) ----------------------------------
__global__ void k_cast(const float* __restrict__ in, ushort* __restrict__ out, int n4) {
  int i = blockIdx.x * 256 + threadIdx.x;
  if (i >= n4) return;
  float4 v = reinterpret_cast<const float4*>(in)[i];
  ushort4 o;
  o.x = f2bf(v.x); o.y = f2bf(v.y); o.z = f2bf(v.z); o.w = f2bf(v.w);
  reinterpret_cast<ushort4*>(out)[i] = o;
}

// ---------------- W_in^T -> bf16 [co][din] -----------------------------------
__global__ void k_winT(const float* __restrict__ Win, ushort* __restrict__ out) {
  int co = blockIdx.x;
  for (int d = threadIdx.x; d < DIN; d += 256)
    out[(size_t)co * DIN + d] = f2bf(Win[(size_t)d * Cc + co]);
}

// ---------------- W_pos^T -> bf16 [co][ci] -----------------------------------
__global__ void k_wpos(const float* __restrict__ Wpos, ushort* __restrict__ out) {
  int co = blockIdx.x, ci = threadIdx.x;
  out[(size_t)co * Cc + ci] = f2bf(Wpos[(size_t)ci * Cc + co]);
}

// ------------- conv_w [l][co][ci][k] -> bf16 [l][co][k*256+ci] ---------------
__global__ void k_wconv(const float* __restrict__ w, ushort* __restrict__ wT) {
  int blk = blockIdx.x;            // l*256 + co
  int tid = threadIdx.x;
  __shared__ ushort t_[Kk][Cc];
  const float* src = w + (size_t)blk * (Cc * Kk);
  for (int i = tid; i < Cc * Kk; i += 256) {
    int ci = i / Kk, k = i - ci * Kk;     // src flat = ci*31 + k
    t_[k][ci] = f2bf(src[i]);
  }
  __syncthreads();
  ushort* dst = wT + (size_t)blk * PCONV;
  const ushort* tf = &t_[0][0];
  for (int i = tid; i < PCONV; i += 256) dst[i] = tf[i];
}

// ---------------- zero the 32 pad rows of each batch in hpad -----------------
__global__ void k_zpad(ushort* __restrict__ hpad) {
  size_t base = (size_t)blockIdx.x * TPAD * Cc;  // pad rows are first 32 rows
  uint4 z = make_uint4(0u, 0u, 0u, 0u);
  for (int i = threadIdx.x; i < (32 * Cc) / 8; i += 256)
    reinterpret_cast<uint4*>(hpad + base)[i] = z;
}

// ---------------- sinusoidal positional embedding -> bf16 --------------------
__global__ void k_pos(const float* __restrict__ rel, ushort* __restrict__ pos) {
  int tid = threadIdx.x;
  int row = blockIdx.x * 4 + (tid >> 6);     // 0..65535 (b*T + t)
  int c0 = (tid & 63) * 4;
  float x = rel[row];
  ushort4 o;
  ushort tmp[4];
#pragma unroll
  for (int j = 0; j < 4; ++j) {
    int c = c0 + j;
    int half = c >> 7;
    int fidx = c & 127;
    float freq = __expf(-9.210340371976184f * (float)fidx * (1.0f / 127.0f));
    float a = x * freq;
    tmp[j] = f2bf(half ? __cosf(a) : __sinf(a));
  }
  o.x = tmp[0]; o.y = tmp[1]; o.z = tmp[2]; o.w = tmp[3];
  *reinterpret_cast<ushort4*>(pos + ((size_t)row << 8) + c0) = o;
}

// ---------------- LayerNorm (+optional exact GELU -> bf16) -------------------
template <int GELU>
__global__ void k_ln(const float* __restrict__ X, const float* __restrict__ g,
                     const float* __restrict__ bta, ushort* __restrict__ H,
                     float* __restrict__ Xout) {
  int tid = threadIdx.x;
  int lane = tid & 63;
  int row = blockIdx.x * 4 + (tid >> 6);
  f32x4 v = reinterpret_cast<const f32x4*>(X + ((size_t)row << 8))[lane];
  float s = v[0] + v[1] + v[2] + v[3];
  float s2 = v[0]*v[0] + v[1]*v[1] + v[2]*v[2] + v[3]*v[3];
#pragma unroll
  for (int off = 32; off; off >>= 1) {
    s += __shfl_xor(s, off);
    s2 += __shfl_xor(s2, off);
  }
  float mu = s * (1.0f / 256.0f);
  float var = s2 * (1.0f / 256.0f) - mu * mu;
  float rs = rsqrtf(var + 1e-5f);
  f32x4 gv = reinterpret_cast<const f32x4*>(g)[lane];
  f32x4 bv = reinterpret_cast<const f32x4*>(bta)[lane];
  f32x4 n;
#pragma unroll
  for (int j = 0; j < 4; ++j) n[j] = (v[j] - mu) * rs * gv[j] + bv[j];
  if (GELU) {
    ushort4 o;
    ushort tmp[4];
#pragma unroll
    for (int j = 0; j < 4; ++j) {
      float x = n[j];
      tmp[j] = f2bf(0.5f * x * (1.0f + erff(x * 0.70710678118654752f)));
    }
    o.x = tmp[0]; o.y = tmp[1]; o.z = tmp[2]; o.w = tmp[3];
    size_t hrow = (size_t)row + ((size_t)(row >> 13) << 5) + 32;  // padded layout
    reinterpret_cast<ushort4*>(H + (hrow << 8))[lane] = o;
  } else {
    reinterpret_cast<f32x4*>(Xout + ((size_t)row << 8))[lane] = n;
  }
}

// ---------------- small-GEMM (modes 0,1), 128x128 tile, BK=64 ----------------
#define BM 128
#define BN 128

template <int MODE>
__global__ __launch_bounds__(256) void k_gemm(
    const ushort* __restrict__ A, const ushort* __restrict__ Bw,
    float* __restrict__ XO, const float* __restrict__ proj,
    const int* __restrict__ idx, const float* __restrict__ bias1,
    int P, int lda) {
  __shared__ __align__(16) char lsA[BM * 64 * 2];
  __shared__ __align__(16) char lsB[BN * 64 * 2];
  int tid = threadIdx.x;
  int tm = blockIdx.x, cn = blockIdx.y, b = blockIdx.z;
  int t0 = tm * BM, co0 = cn * BN;
  int lane = tid & 63, wid = tid >> 6;
  int wm = wid >> 1, wn = wid & 1;
  int srow = lane >> 3;
  int scol = ((lane & 7) ^ srow) << 3;
  size_t rowoff = (MODE == 1) ? (size_t)b * Tt : 0;

  f32x4 acc[4][4];
#pragma unroll
  for (int i = 0; i < 4; ++i)
#pragma unroll
    for (int j = 0; j < 4; ++j) acc[i][j] = (f32x4){0.f, 0.f, 0.f, 0.f};

  int steps = P >> 6;
  for (int s = 0; s < steps; ++s) {
    int ci0 = s << 6;
    __syncthreads();
#pragma unroll
    for (int i = 0; i < 4; ++i) {
      int j = (wid << 2) + i;           // chunk 0..15
      int r = (j << 3) + srow;
      const ushort* ga = A + (rowoff + (size_t)(t0 + r)) * lda + ci0 + scol;
      gload16(ga, lsA + (j << 10));
      const ushort* gb = Bw + (size_t)(co0 + r) * P + ci0 + scol;
      gload16(gb, lsB + (j << 10));
    }
    __syncthreads();
#pragma unroll
    for (int h2 = 0; h2 < 2; ++h2) {
      int kb = h2 * 64 + ((lane >> 4) << 4);
      short8 af[4], bf[4];
#pragma unroll
      for (int fi = 0; fi < 4; ++fi) {
        int ra = wm * 64 + fi * 16 + (lane & 15);
        af[fi] = *reinterpret_cast<const short8*>(lsA + ((ra * 128 + kb) ^ ((ra & 7) << 4)));
        int rb = wn * 64 + fi * 16 + (lane & 15);
        bf[fi] = *reinterpret_cast<const short8*>(lsB + ((rb * 128 + kb) ^ ((rb & 7) << 4)));
      }
#pragma unroll
      for (int fi = 0; fi < 4; ++fi)
#pragma unroll
        for (int fj = 0; fj < 4; ++fj)
          acc[fi][fj] = __builtin_amdgcn_mfma_f32_16x16x32_bf16(af[fi], bf[fj], acc[fi][fj], 0, 0, 0);
    }
  }
  size_t rowbase = (size_t)b * Tt;
#pragma unroll
  for (int fi = 0; fi < 4; ++fi) {
#pragma unroll
    for (int fj = 0; fj < 4; ++fj) {
#pragma unroll
      for (int r = 0; r < 4; ++r) {
        int row = t0 + wm * 64 + fi * 16 + ((lane >> 4) << 2) + r;
        int col = co0 + wn * 64 + fj * 16 + (lane & 15);
        size_t go = ((rowbase + row) << 8) + col;
        float v = acc[fi][fj][r];
        if (MODE == 0) {
          XO[go] = v + bias1[col];
        } else {
          int ix = idx[b * Tt + row];
          ix = min(max(ix, 0), Nn - 1);
          XO[go] = v + proj[((size_t)(b * Nn + ix) << 8) + col] + bias1[col];
        }
      }
    }
  }
}

// ======= conv GEMM: 256x256 tile, BK=64, 8 waves, 4-phase counted-vmcnt ======
// A = hpad (im2col via row shift, A addr advances +64 elem / K-step)
// B = wT3 layer [256][7936]; out: X += conv + bias (residual)
__global__ __launch_bounds__(512, 2) void k_conv256(
    const ushort* __restrict__ A, const ushort* __restrict__ Bw,
    float* __restrict__ XO, const float* __restrict__ bias1) {
  __shared__ __align__(16) char lds[131072];
  char* lsA = lds;             // 2 bufs x 32 KiB
  char* lsB = lds + 65536;     // 2 bufs x 32 KiB
  int tid = threadIdx.x;
  int lane = tid & 63, wid = tid >> 6;
  int wm = wid >> 2, wn = wid & 3;         // 2M x 4N waves
  int tm = blockIdx.x, b = blockIdx.y;
  int t0 = tm * 256;
  int l3 = lane >> 3;
  int swz = ((lane & 7) ^ l3) << 3;        // pre-swizzled source col (elems)
  int l15 = lane & 15;
  int khi = (lane >> 4) << 4;              // k-chunk byte offset
  int xorl = (lane & 7) << 4;              // read-side swizzle term (== (row&7)<<4)
  int db0 = (wid & 3) + ((wid >> 2) << 3);

  // per-role source pointers at K-step 0 (A addr = row*256 + 512 + s*64 + swz)
  size_t abase = (size_t)b * TPAD + t0;
  const ushort* pa0 = A + (abase + (size_t)(wid)      * 8 + l3) * 256 + 512 + swz;
  const ushort* pa1 = A + (abase + (size_t)(wid + 16) * 8 + l3) * 256 + 512 + swz;
  const ushort* pa2 = A + (abase + (size_t)(wid + 8)  * 8 + l3) * 256 + 512 + swz;
  const ushort* pa3 = A + (abase + (size_t)(wid + 24) * 8 + l3) * 256 + 512 + swz;
  const ushort* pb0 = Bw + ((size_t)(db0)      * 8 + l3) * PCONV + swz;
  const ushort* pb1 = Bw + ((size_t)(db0 + 16) * 8 + l3) * PCONV + swz;
  const ushort* pb2 = Bw + ((size_t)(db0 + 4)  * 8 + l3) * PCONV + swz;
  const ushort* pb3 = Bw + ((size_t)(db0 + 20) * 8 + l3) * PCONV + swz;

  f32x4 acc[8][4];
#pragma unroll
  for (int i = 0; i < 8; ++i)
#pragma unroll
    for (int j = 0; j < 4; ++j) acc[i][j] = (f32x4){0.f, 0.f, 0.f, 0.f};

  // prologue: stage K-step 0 into buf 0, group order A0,B0,B1,A1
  gload16(pa0, lsA + (size_t)(wid)      * 1024);
  gload16(pa1, lsA + (size_t)(wid + 16) * 1024); pa0 += 64; pa1 += 64;
  gload16(pb0, lsB + (size_t)(db0)      * 1024);
  gload16(pb1, lsB + (size_t)(db0 + 16) * 1024); pb0 += 64; pb1 += 64;
  gload16(pb2, lsB + (size_t)(db0 + 4)  * 1024);
  gload16(pb3, lsB + (size_t)(db0 + 20) * 1024); pb2 += 64; pb3 += 64;
  gload16(pa2, lsA + (size_t)(wid + 8)  * 1024);
  gload16(pa3, lsA + (size_t)(wid + 24) * 1024); pa2 += 64; pa3 += 64;

  int cur = 0;
  for (int t = 0; t < NT; ++t, cur ^= 1) {
    int nb = cur ^ 1;
    char* dA = lsA + nb * 32768;
    char* dB = lsB + nb * 32768;
    char* bA = lsA + cur * 32768;
    char* bB = lsB + cur * 32768;
#pragma unroll
    for (int p = 0; p < 4; ++p) {
      const int mh = p >> 1, nh = p & 1;
      if (p < 3) asm volatile("s_waitcnt vmcnt(4)" ::: "memory");
      __builtin_amdgcn_s_barrier();
      asm volatile("" ::: "memory");
      // stage one group of K-step t+1 into buf nb (last tile stages garbage; unused)
      if (p == 0) { gload16(pa0, dA + (size_t)(wid)      * 1024);
                    gload16(pa1, dA + (size_t)(wid + 16) * 1024); pa0 += 64; pa1 += 64; }
      if (p == 1) { gload16(pb0, dB + (size_t)(db0)      * 1024);
                    gload16(pb1, dB + (size_t)(db0 + 16) * 1024); pb0 += 64; pb1 += 64; }
      if (p == 2) { gload16(pb2, dB + (size_t)(db0 + 4)  * 1024);
                    gload16(pb3, dB + (size_t)(db0 + 20) * 1024); pb2 += 64; pb3 += 64; }
      if (p == 3) { gload16(pa2, dA + (size_t)(wid + 8)  * 1024);
                    gload16(pa3, dA + (size_t)(wid + 24) * 1024); pa2 += 64; pa3 += 64; }
      // ds_read this phase's fragments from buf cur
      short8 af[2][4], bfr[2][2];
#pragma unroll
      for (int kk = 0; kk < 2; ++kk) {
#pragma unroll
        for (int fi = 0; fi < 4; ++fi) {
          int ra = wm * 128 + mh * 64 + fi * 16 + l15;
          af[kk][fi] = *reinterpret_cast<const short8*>(bA + ((ra * 128 + kk * 64 + khi) ^ xorl));
        }
#pragma unroll
        for (int j2 = 0; j2 < 2; ++j2) {
          int rb = wn * 64 + nh * 32 + j2 * 16 + l15;
          bfr[kk][j2] = *reinterpret_cast<const short8*>(bB + ((rb * 128 + kk * 64 + khi) ^ xorl));
        }
      }
      __builtin_amdgcn_s_setprio(1);
#pragma unroll
      for (int fi = 0; fi < 4; ++fi)
#pragma unroll
        for (int j2 = 0; j2 < 2; ++j2) {
          acc[mh*4+fi][nh*2+j2] = __builtin_amdgcn_mfma_f32_16x16x32_bf16(af[0][fi], bfr[0][j2], acc[mh*4+fi][nh*2+j2], 0, 0, 0);
          acc[mh*4+fi][nh*2+j2] = __builtin_amdgcn_mfma_f32_16x16x32_bf16(af[1][fi], bfr[1][j2], acc[mh*4+fi][nh*2+j2], 0, 0, 0);
        }
      __builtin_amdgcn_s_setprio(0);
    }
  }
  // epilogue: X += acc + bias  (C/D: col=lane&15, row=(lane>>4)*4+rr)
  size_t rowb = (size_t)b * Tt;
#pragma unroll
  for (int fj = 0; fj < 4; ++fj) {
    int col = wn * 64 + fj * 16 + l15;
    float bv = bias1[col];
#pragma unroll
    for (int fi = 0; fi < 8; ++fi) {
#pragma unroll
      for (int rr = 0; rr < 4; ++rr) {
        int row = t0 + wm * 128 + fi * 16 + ((lane >> 4) << 2) + rr;
        size_t go = ((rowb + row) << 8) + col;
        XO[go] += acc[fi][fj][rr] + bv;
      }
    }
  }
}

extern "C" void kernel_launch(void* const* d_in, const int* in_sizes, int n_in,
                              void* d_out, int out_size, void* d_ws, size_t ws_size,
                              hipStream_t stream) {
  const float* pooled = (const float*)d_in[0];
  const int*   durations = (const int*)d_in[1];
  const float* rel  = (const float*)d_in[2];
  const float* Win  = (const float*)d_in[3];
  const float* bin  = (const float*)d_in[4];
  const float* Wpos = (const float*)d_in[5];
  const float* bpos = (const float*)d_in[6];
  const float* lng  = (const float*)d_in[7];
  const float* lnb  = (const float*)d_in[8];
  const float* convw = (const float*)d_in[9];
  const float* convb = (const float*)d_in[10];
  const float* outg = (const float*)d_in[11];
  const float* outb = (const float*)d_in[12];
  float* X = (float*)d_out;

  char* ws = (char*)d_ws;
  int*    idx      = (int*)ws;                          // 256 KB
  float*  proj     = (float*)(ws + 262144);             // 8 MB      -> end  8650752
  ushort* pos      = (ushort*)(ws + 8650752);           // 32 MB (pos emb; later hpad)
  ushort* hpad     = (ushort*)(ws + 8650752);           // 33.7 MB   -> end 42336256
  ushort* wposT    = (ushort*)(ws + 42336256);          // 128 KB    -> end 42467328
  ushort* wT3      = (ushort*)(ws + 42467328);          // 11.6 MB   -> end 54657024
  ushort* pooledbf = (ushort*)(ws + 54657024);          // 8 MB      -> end 63045632
  ushort* winT     = (ushort*)(ws + 63045632);          // 256 KB    -> end 63307776

  k_idx<<<Bb, Nn, 0, stream>>>(durations, idx);
  k_cast<<<4096, 256, 0, stream>>>(pooled, pooledbf, (Bb * Nn * DIN) / 4);
  k_winT<<<Cc, 256, 0, stream>>>(Win, winT);
  k_wconv<<<Ll * Cc, 256, 0, stream>>>(convw, wT3);
  k_wpos<<<Cc, Cc, 0, stream>>>(Wpos, wposT);
  k_pos<<<(Bb * Tt) / 4, 256, 0, stream>>>(rel, pos);

  // in_proj: proj[n, co] = pooled @ W_in + b_in    (8192 x 512 x 256)
  k_gemm<0><<<dim3(64, 2, 1), 256, 0, stream>>>(pooledbf, winT, proj, nullptr, nullptr, bin, DIN, DIN);
  // x = gather(proj, idx) + pos @ W_pos + b_pos    (65536 x 256 x 256)
  k_gemm<1><<<dim3(64, 2, Bb), 256, 0, stream>>>(pos, wposT, X, proj, idx, bpos, Cc, Cc);
  // pos consumed -> region becomes hpad; zero the pad rows once
  k_zpad<<<Bb, 256, 0, stream>>>(hpad);

  for (int l = 0; l < Ll; ++l) {
    k_ln<1><<<(Bb * Tt) / 4, 256, 0, stream>>>(X, lng + l * Cc, lnb + l * Cc, hpad, nullptr);
    k_conv256<<<dim3(32, Bb), 512, 0, stream>>>(hpad, wT3 + (size_t)l * Cc * PCONV, X, convb + l * Cc);
  }
  k_ln<0><<<(Bb * Tt) / 4, 256, 0, stream>>>(X, outg, outb, nullptr, X);
}

// Round 10
// 963.951 us; speedup vs baseline: 1.7303x; 1.0202x over previous
//
#include <hip/hip_runtime.h>
#include <hip/hip_bf16.h>

#define Bb 8
#define Nn 1024
#define DIN 512
#define Cc 256
#define Tt 8192
#define Kk 31
#define Ll 3
#define PCONV (Kk*Cc)   // 7936
#define TPAD (Tt+32)    // 32 zero rows in front of each batch of h
#define NT 124          // 4 ci-chunks x 31 k-taps

typedef __attribute__((ext_vector_type(8))) short short8;
typedef __attribute__((ext_vector_type(4))) float f32x4;

__device__ __forceinline__ ushort f2bf(float f) {
  union { __hip_bfloat16 h; unsigned short u; } cv;
  cv.h = __float2bfloat16(f);
  return cv.u;
}

// direct global->LDS DMA, 16B per lane; LDS ptr wave-uniform (HW adds lane*16)
__device__ __forceinline__ void gload16(const void* g, void* l) {
  __builtin_amdgcn_global_load_lds((const __attribute__((address_space(1))) void*)g,
                                   (__attribute__((address_space(3))) void*)l, 16, 0, 0);
}

// ---------------- idx: per-batch cumsum of durations + scatter fill ----------
__global__ void k_idx(const int* __restrict__ dur, int* __restrict__ idx) {
  int b = blockIdx.x, tid = threadIdx.x;
  __shared__ int cum[Nn];
  int d = dur[b * Nn + tid];
  cum[tid] = d;
  __syncthreads();
  for (int off = 1; off < Nn; off <<= 1) {
    int o = (tid >= off) ? cum[tid - off] : 0;
    __syncthreads();
    cum[tid] += o;
    __syncthreads();
  }
  int end = cum[tid], start = end - d;
  if (start < 0) start = 0;
  if (end > Tt) end = Tt;
  for (int t = start; t < end; ++t) idx[b * Tt + t] = tid;
}

// ---------------- f32 -> bf16 cast (pooled) ----------------------------------
__global__ void k_cast(const float* __restrict__ in, ushort* __restrict__ out, int n4) {
  int i = blockIdx.x * 256 + threadIdx.x;
  if (i >= n4) return;
  float4 v = reinterpret_cast<const float4*>(in)[i];
  ushort4 o;
  o.x = f2bf(v.x); o.y = f2bf(v.y); o.z = f2bf(v.z); o.w = f2bf(v.w);
  reinterpret_cast<ushort4*>(out)[i] = o;
}

// ---------------- W_in^T -> bf16 [co][din] -----------------------------------
__global__ void k_winT(const float* __restrict__ Win, ushort* __restrict__ out) {
  int co = blockIdx.x;
  for (int d = threadIdx.x; d < DIN; d += 256)
    out[(size_t)co * DIN + d] = f2bf(Win[(size_t)d * Cc + co]);
}

// ---------------- W_pos^T -> bf16 [co][ci] -----------------------------------
__global__ void k_wpos(const float* __restrict__ Wpos, ushort* __restrict__ out) {
  int co = blockIdx.x, ci = threadIdx.x;
  out[(size_t)co * Cc + ci] = f2bf(Wpos[(size_t)ci * Cc + co]);
}

// --- conv_w [l][co][ci][k] -> bf16 [l][co][p], p=(cc*31+k)*64+(ci&63), cc=ci>>6
__global__ void k_wconv(const float* __restrict__ w, ushort* __restrict__ wT) {
  int blk = blockIdx.x;            // l*256 + co
  int tid = threadIdx.x;
  __shared__ ushort t_[Kk][Cc];
  const float* src = w + (size_t)blk * (Cc * Kk);
  for (int i = tid; i < Cc * Kk; i += 256) {
    int ci = i / Kk, k = i - ci * Kk;     // src flat = ci*31 + k
    t_[k][ci] = f2bf(src[i]);
  }
  __syncthreads();
  ushort* dst = wT + (size_t)blk * PCONV;
  for (int p = tid; p < PCONV; p += 256) {
    int c6 = p & 63;
    int q = p >> 6;           // 0..123 = cc*31 + k
    int cc = q / 31;
    int k = q - cc * 31;
    dst[p] = t_[k][cc * 64 + c6];
  }
}

// ---------------- zero the 32 pad rows of each batch in hpad -----------------
__global__ void k_zpad(ushort* __restrict__ hpad) {
  size_t base = (size_t)blockIdx.x * TPAD * Cc;  // pad rows are first 32 rows
  uint4 z = make_uint4(0u, 0u, 0u, 0u);
  for (int i = threadIdx.x; i < (32 * Cc) / 8; i += 256)
    reinterpret_cast<uint4*>(hpad + base)[i] = z;
}

// ---------------- sinusoidal positional embedding -> bf16 --------------------
__global__ void k_pos(const float* __restrict__ rel, ushort* __restrict__ pos) {
  int tid = threadIdx.x;
  int row = blockIdx.x * 4 + (tid >> 6);     // 0..65535 (b*T + t)
  int c0 = (tid & 63) * 4;
  float x = rel[row];
  ushort4 o;
  ushort tmp[4];
#pragma unroll
  for (int j = 0; j < 4; ++j) {
    int c = c0 + j;
    int half = c >> 7;
    int fidx = c & 127;
    float freq = __expf(-9.210340371976184f * (float)fidx * (1.0f / 127.0f));
    float a = x * freq;
    tmp[j] = f2bf(half ? __cosf(a) : __sinf(a));
  }
  o.x = tmp[0]; o.y = tmp[1]; o.z = tmp[2]; o.w = tmp[3];
  *reinterpret_cast<ushort4*>(pos + ((size_t)row << 8) + c0) = o;
}

// ---------------- LayerNorm (+optional exact GELU -> bf16) -------------------
template <int GELU>
__global__ void k_ln(const float* __restrict__ X, const float* __restrict__ g,
                     const float* __restrict__ bta, ushort* __restrict__ H,
                     float* __restrict__ Xout) {
  int tid = threadIdx.x;
  int lane = tid & 63;
  int row = blockIdx.x * 4 + (tid >> 6);
  f32x4 v = reinterpret_cast<const f32x4*>(X + ((size_t)row << 8))[lane];
  float s = v[0] + v[1] + v[2] + v[3];
  float s2 = v[0]*v[0] + v[1]*v[1] + v[2]*v[2] + v[3]*v[3];
#pragma unroll
  for (int off = 32; off; off >>= 1) {
    s += __shfl_xor(s, off);
    s2 += __shfl_xor(s2, off);
  }
  float mu = s * (1.0f / 256.0f);
  float var = s2 * (1.0f / 256.0f) - mu * mu;
  float rs = rsqrtf(var + 1e-5f);
  f32x4 gv = reinterpret_cast<const f32x4*>(g)[lane];
  f32x4 bv = reinterpret_cast<const f32x4*>(bta)[lane];
  f32x4 n;
#pragma unroll
  for (int j = 0; j < 4; ++j) n[j] = (v[j] - mu) * rs * gv[j] + bv[j];
  if (GELU) {
    ushort4 o;
    ushort tmp[4];
#pragma unroll
    for (int j = 0; j < 4; ++j) {
      float x = n[j];
      tmp[j] = f2bf(0.5f * x * (1.0f + erff(x * 0.70710678118654752f)));
    }
    o.x = tmp[0]; o.y = tmp[1]; o.z = tmp[2]; o.w = tmp[3];
    size_t hrow = (size_t)row + ((size_t)(row >> 13) << 5) + 32;  // padded layout
    reinterpret_cast<ushort4*>(H + (hrow << 8))[lane] = o;
  } else {
    reinterpret_cast<f32x4*>(Xout + ((size_t)row << 8))[lane] = n;
  }
}

// ---------------- small-GEMM (modes 0,1), 128x128 tile, BK=64 ----------------
#define BM 128
#define BN 128

template <int MODE>
__global__ __launch_bounds__(256) void k_gemm(
    const ushort* __restrict__ A, const ushort* __restrict__ Bw,
    float* __restrict__ XO, const float* __restrict__ proj,
    const int* __restrict__ idx, const float* __restrict__ bias1,
    int P, int lda) {
  __shared__ __align__(16) char lsA[BM * 64 * 2];
  __shared__ __align__(16) char lsB[BN * 64 * 2];
  int tid = threadIdx.x;
  int tm = blockIdx.x, cn = blockIdx.y, b = blockIdx.z;
  int t0 = tm * BM, co0 = cn * BN;
  int lane = tid & 63, wid = tid >> 6;
  int wm = wid >> 1, wn = wid & 1;
  int srow = lane >> 3;
  int scol = ((lane & 7) ^ srow) << 3;
  size_t rowoff = (MODE == 1) ? (size_t)b * Tt : 0;

  f32x4 acc[4][4];
#pragma unroll
  for (int i = 0; i < 4; ++i)
#pragma unroll
    for (int j = 0; j < 4; ++j) acc[i][j] = (f32x4){0.f, 0.f, 0.f, 0.f};

  int steps = P >> 6;
  for (int s = 0; s < steps; ++s) {
    int ci0 = s << 6;
    __syncthreads();
#pragma unroll
    for (int i = 0; i < 4; ++i) {
      int j = (wid << 2) + i;           // chunk 0..15
      int r = (j << 3) + srow;
      const ushort* ga = A + (rowoff + (size_t)(t0 + r)) * lda + ci0 + scol;
      gload16(ga, lsA + (j << 10));
      const ushort* gb = Bw + (size_t)(co0 + r) * P + ci0 + scol;
      gload16(gb, lsB + (j << 10));
    }
    __syncthreads();
#pragma unroll
    for (int h2 = 0; h2 < 2; ++h2) {
      int kb = h2 * 64 + ((lane >> 4) << 4);
      short8 af[4], bf[4];
#pragma unroll
      for (int fi = 0; fi < 4; ++fi) {
        int ra = wm * 64 + fi * 16 + (lane & 15);
        af[fi] = *reinterpret_cast<const short8*>(lsA + ((ra * 128 + kb) ^ ((ra & 7) << 4)));
        int rb = wn * 64 + fi * 16 + (lane & 15);
        bf[fi] = *reinterpret_cast<const short8*>(lsB + ((rb * 128 + kb) ^ ((rb & 7) << 4)));
      }
#pragma unroll
      for (int fi = 0; fi < 4; ++fi)
#pragma unroll
        for (int fj = 0; fj < 4; ++fj)
          acc[fi][fj] = __builtin_amdgcn_mfma_f32_16x16x32_bf16(af[fi], bf[fj], acc[fi][fj], 0, 0, 0);
    }
  }
  size_t rowbase = (size_t)b * Tt;
#pragma unroll
  for (int fi = 0; fi < 4; ++fi) {
#pragma unroll
    for (int fj = 0; fj < 4; ++fj) {
#pragma unroll
      for (int r = 0; r < 4; ++r) {
        int row = t0 + wm * 64 + fi * 16 + ((lane >> 4) << 2) + r;
        int col = co0 + wn * 64 + fj * 16 + (lane & 15);
        size_t go = ((rowbase + row) << 8) + col;
        float v = acc[fi][fj][r];
        if (MODE == 0) {
          XO[go] = v + bias1[col];
        } else {
          int ix = idx[b * Tt + row];
          ix = min(max(ix, 0), Nn - 1);
          XO[go] = v + proj[((size_t)(b * Nn + ix) << 8) + col] + bias1[col];
        }
      }
    }
  }
}

// ======= conv GEMM: 256x256 tile, BK=64, 8 waves, 4-phase counted-vmcnt ======
// K-step order: ci-chunk OUTER, k-tap INNER (s = cc*31 + k) -> A tile slides
// 1 row/step, 31x reuse within a 31-step window => L2-resident A working set.
// A addr step: +256 elem within chunk; 64-30*256 at chunk boundary.
// B = wT3 layer [256][7936] repacked to match (p = s*64 + c6): +64/step.
__global__ __launch_bounds__(512, 2) void k_conv256(
    const ushort* __restrict__ A, const ushort* __restrict__ Bw,
    float* __restrict__ XO, const float* __restrict__ bias1) {
  __shared__ __align__(16) char lds[131072];
  char* lsA = lds;             // 2 bufs x 32 KiB
  char* lsB = lds + 65536;     // 2 bufs x 32 KiB
  int tid = threadIdx.x;
  int lane = tid & 63, wid = tid >> 6;
  int wm = wid >> 2, wn = wid & 3;         // 2M x 4N waves
  int tm = blockIdx.x, b = blockIdx.y;
  int t0 = tm * 256;
  int l3 = lane >> 3;
  int swz = ((lane & 7) ^ l3) << 3;        // pre-swizzled source col (elems)
  int l15 = lane & 15;
  int khi = (lane >> 4) << 4;              // k-chunk byte offset
  int xorl = (lane & 7) << 4;              // read-side swizzle term (== (row&7)<<4)
  int db0 = (wid & 3) + ((wid >> 2) << 3);

  // per-role source pointers at K-step 0 (A addr = row*256 + 512 + k*256 + cc*64)
  size_t abase = (size_t)b * TPAD + t0;
  const ushort* pa0 = A + (abase + (size_t)(wid)      * 8 + l3) * 256 + 512 + swz;
  const ushort* pa1 = A + (abase + (size_t)(wid + 16) * 8 + l3) * 256 + 512 + swz;
  const ushort* pa2 = A + (abase + (size_t)(wid + 8)  * 8 + l3) * 256 + 512 + swz;
  const ushort* pa3 = A + (abase + (size_t)(wid + 24) * 8 + l3) * 256 + 512 + swz;
  const ushort* pb0 = Bw + ((size_t)(db0)      * 8 + l3) * PCONV + swz;
  const ushort* pb1 = Bw + ((size_t)(db0 + 16) * 8 + l3) * PCONV + swz;
  const ushort* pb2 = Bw + ((size_t)(db0 + 4)  * 8 + l3) * PCONV + swz;
  const ushort* pb3 = Bw + ((size_t)(db0 + 20) * 8 + l3) * PCONV + swz;

  f32x4 acc[8][4];
#pragma unroll
  for (int i = 0; i < 8; ++i)
#pragma unroll
    for (int j = 0; j < 4; ++j) acc[i][j] = (f32x4){0.f, 0.f, 0.f, 0.f};

  // prologue: stage K-step 0 into buf 0, group order A0,B0,B1,A1; advance to s=1
  gload16(pa0, lsA + (size_t)(wid)      * 1024);
  gload16(pa1, lsA + (size_t)(wid + 16) * 1024); pa0 += 256; pa1 += 256;
  gload16(pb0, lsB + (size_t)(db0)      * 1024);
  gload16(pb1, lsB + (size_t)(db0 + 16) * 1024); pb0 += 64; pb1 += 64;
  gload16(pb2, lsB + (size_t)(db0 + 4)  * 1024);
  gload16(pb3, lsB + (size_t)(db0 + 20) * 1024); pb2 += 64; pb3 += 64;
  gload16(pa2, lsA + (size_t)(wid + 8)  * 1024);
  gload16(pa3, lsA + (size_t)(wid + 24) * 1024); pa2 += 256; pa3 += 256;

  int cur = 0;
  for (int t = 0; t < NT; ++t, cur ^= 1) {
    int nb = cur ^ 1;
    char* dA = lsA + nb * 32768;
    char* dB = lsB + nb * 32768;
    char* bA = lsA + cur * 32768;
    char* bB = lsB + cur * 32768;
    // delta from staged step (t+1) to next (t+2): chunk jump when (t+2)%31==0
    int adel = ((t + 2) % 31 == 0) ? (64 - 30 * 256) : 256;
#pragma unroll
    for (int p = 0; p < 4; ++p) {
      const int mh = p >> 1, nh = p & 1;
      if (p < 3) asm volatile("s_waitcnt vmcnt(4)" ::: "memory");
      __builtin_amdgcn_s_barrier();
      asm volatile("" ::: "memory");
      // stage one group of K-step t+1 into buf nb (last tile stages garbage; unused)
      if (p == 0) { gload16(pa0, dA + (size_t)(wid)      * 1024);
                    gload16(pa1, dA + (size_t)(wid + 16) * 1024); pa0 += adel; pa1 += adel; }
      if (p == 1) { gload16(pb0, dB + (size_t)(db0)      * 1024);
                    gload16(pb1, dB + (size_t)(db0 + 16) * 1024); pb0 += 64; pb1 += 64; }
      if (p == 2) { gload16(pb2, dB + (size_t)(db0 + 4)  * 1024);
                    gload16(pb3, dB + (size_t)(db0 + 20) * 1024); pb2 += 64; pb3 += 64; }
      if (p == 3) { gload16(pa2, dA + (size_t)(wid + 8)  * 1024);
                    gload16(pa3, dA + (size_t)(wid + 24) * 1024); pa2 += adel; pa3 += adel; }
      // ds_read this phase's fragments from buf cur
      short8 af[2][4], bfr[2][2];
#pragma unroll
      for (int kk = 0; kk < 2; ++kk) {
#pragma unroll
        for (int fi = 0; fi < 4; ++fi) {
          int ra = wm * 128 + mh * 64 + fi * 16 + l15;
          af[kk][fi] = *reinterpret_cast<const short8*>(bA + ((ra * 128 + kk * 64 + khi) ^ xorl));
        }
#pragma unroll
        for (int j2 = 0; j2 < 2; ++j2) {
          int rb = wn * 64 + nh * 32 + j2 * 16 + l15;
          bfr[kk][j2] = *reinterpret_cast<const short8*>(bB + ((rb * 128 + kk * 64 + khi) ^ xorl));
        }
      }
      __builtin_amdgcn_s_setprio(1);
#pragma unroll
      for (int fi = 0; fi < 4; ++fi)
#pragma unroll
        for (int j2 = 0; j2 < 2; ++j2) {
          acc[mh*4+fi][nh*2+j2] = __builtin_amdgcn_mfma_f32_16x16x32_bf16(af[0][fi], bfr[0][j2], acc[mh*4+fi][nh*2+j2], 0, 0, 0);
          acc[mh*4+fi][nh*2+j2] = __builtin_amdgcn_mfma_f32_16x16x32_bf16(af[1][fi], bfr[1][j2], acc[mh*4+fi][nh*2+j2], 0, 0, 0);
        }
      __builtin_amdgcn_s_setprio(0);
    }
  }
  // epilogue: X += acc + bias  (C/D: col=lane&15, row=(lane>>4)*4+rr)
  size_t rowb = (size_t)b * Tt;
#pragma unroll
  for (int fj = 0; fj < 4; ++fj) {
    int col = wn * 64 + fj * 16 + l15;
    float bv = bias1[col];
#pragma unroll
    for (int fi = 0; fi < 8; ++fi) {
#pragma unroll
      for (int rr = 0; rr < 4; ++rr) {
        int row = t0 + wm * 128 + fi * 16 + ((lane >> 4) << 2) + rr;
        size_t go = ((rowb + row) << 8) + col;
        XO[go] += acc[fi][fj][rr] + bv;
      }
    }
  }
}

extern "C" void kernel_launch(void* const* d_in, const int* in_sizes, int n_in,
                              void* d_out, int out_size, void* d_ws, size_t ws_size,
                              hipStream_t stream) {
  const float* pooled = (const float*)d_in[0];
  const int*   durations = (const int*)d_in[1];
  const float* rel  = (const float*)d_in[2];
  const float* Win  = (const float*)d_in[3];
  const float* bin  = (const float*)d_in[4];
  const float* Wpos = (const float*)d_in[5];
  const float* bpos = (const float*)d_in[6];
  const float* lng  = (const float*)d_in[7];
  const float* lnb  = (const float*)d_in[8];
  const float* convw = (const float*)d_in[9];
  const float* convb = (const float*)d_in[10];
  const float* outg = (const float*)d_in[11];
  const float* outb = (const float*)d_in[12];
  float* X = (float*)d_out;

  char* ws = (char*)d_ws;
  int*    idx      = (int*)ws;                          // 256 KB
  float*  proj     = (float*)(ws + 262144);             // 8 MB      -> end  8650752
  ushort* pos      = (ushort*)(ws + 8650752);           // 32 MB (pos emb; later hpad)
  ushort* hpad     = (ushort*)(ws + 8650752);           // 33.7 MB   -> end 42336256
  ushort* wposT    = (ushort*)(ws + 42336256);          // 128 KB    -> end 42467328
  ushort* wT3      = (ushort*)(ws + 42467328);          // 11.6 MB   -> end 54657024
  ushort* pooledbf = (ushort*)(ws + 54657024);          // 8 MB      -> end 63045632
  ushort* winT     = (ushort*)(ws + 63045632);          // 256 KB    -> end 63307776

  k_idx<<<Bb, Nn, 0, stream>>>(durations, idx);
  k_cast<<<4096, 256, 0, stream>>>(pooled, pooledbf, (Bb * Nn * DIN) / 4);
  k_winT<<<Cc, 256, 0, stream>>>(Win, winT);
  k_wconv<<<Ll * Cc, 256, 0, stream>>>(convw, wT3);
  k_wpos<<<Cc, Cc, 0, stream>>>(Wpos, wposT);
  k_pos<<<(Bb * Tt) / 4, 256, 0, stream>>>(rel, pos);

  // in_proj: proj[n, co] = pooled @ W_in + b_in    (8192 x 512 x 256)
  k_gemm<0><<<dim3(64, 2, 1), 256, 0, stream>>>(pooledbf, winT, proj, nullptr, nullptr, bin, DIN, DIN);
  // x = gather(proj, idx) + pos @ W_pos + b_pos    (65536 x 256 x 256)
  k_gemm<1><<<dim3(64, 2, Bb), 256, 0, stream>>>(pos, wposT, X, proj, idx, bpos, Cc, Cc);
  // pos consumed -> region becomes hpad; zero the pad rows once
  k_zpad<<<Bb, 256, 0, stream>>>(hpad);

  for (int l = 0; l < Ll; ++l) {
    k_ln<1><<<(Bb * Tt) / 4, 256, 0, stream>>>(X, lng + l * Cc, lnb + l * Cc, hpad, nullptr);
    k_conv256<<<dim3(32, Bb), 512, 0, stream>>>(hpad, wT3 + (size_t)l * Cc * PCONV, X, convb + l * Cc);
  }
  k_ln<0><<<(Bb * Tt) / 4, 256, 0, stream>>>(X, outg, outb, nullptr, X);
}